// Round 1
// baseline (194.413 us; speedup 1.0000x reference)
//
#include <hip/hip_runtime.h>

#define NQ 19
#define SZ (1u << NQ)

// ---------------------------------------------------------------------------
// Prep: GCN front-end (fp64), fused gate matrices G[6][19(bit)][4], phase
// tables T0[1024] (bits 0..9, includes -S/2) and T1[512] (bits 10..18).
// Qubit q <-> flat-index bit k = 18 - q  (C-order flatten of (2,)*19).
// Fused ansatz 1q gate: U = RZ(t)*RX(t), c=cos(t/2), s=sin(t/2):
//   u00=(c^2,-sc) u01=(-s^2,-cs) u10=(s^2,-cs) u11=(c^2,sc)
// ---------------------------------------------------------------------------
__global__ __launch_bounds__(128)
void k_prep(const int* __restrict__ ei, const float* __restrict__ state,
            const float* __restrict__ mass, const float* __restrict__ spin,
            const float* __restrict__ charge, const float* __restrict__ p_norm,
            const float* __restrict__ theta,
            const float* __restrict__ gnw, const float* __restrict__ gnb,
            const float* __restrict__ gew, const float* __restrict__ geb,
            const float* __restrict__ nw, const float* __restrict__ nb,
            const float* __restrict__ ew, const float* __restrict__ eb,
            const float* __restrict__ qw,
            double2* __restrict__ G, double* __restrict__ T0,
            double* __restrict__ T1)
{
    __shared__ double feats[NQ];
    int tid = threadIdx.x;
    if (tid == 0) {
        double deg[8], dis[8], h[8], o1[8], he[8], o2[8];
        for (int v = 0; v < 8; ++v) deg[v] = 1.0;                 // self loops
        for (int e = 0; e < 8; ++e) deg[ei[8 + e]] += 1.0;
        for (int v = 0; v < 8; ++v) dis[v] = 1.0 / sqrt(deg[v]);
        // node GCN: h = state @ gcn_node_w  (4 -> 1)
        for (int v = 0; v < 8; ++v) {
            double s = 0.0;
            for (int k = 0; k < 4; ++k) s += (double)state[v * 4 + k] * (double)gnw[k];
            h[v] = s;
        }
        for (int v = 0; v < 8; ++v) o1[v] = h[v] * dis[v] * dis[v] + (double)gnb[0];
        for (int e = 0; e < 8; ++e) {
            int s = ei[e], d = ei[8 + e];
            o1[d] += h[s] * dis[s] * dis[d];
        }
        for (int j = 0; j < 9; ++j) {
            double a = (double)nb[j];
            for (int v = 0; v < 8; ++v) a += o1[v] * (double)nw[v * 9 + j];
            feats[j] = a;
        }
        // edge GCN: x_edges = [mass,spin,charge]  (3 -> 1), same graph (n=8)
        for (int e = 0; e < 8; ++e)
            he[e] = (double)mass[e] * (double)gew[0] + (double)spin[e] * (double)gew[1]
                  + (double)charge[e] * (double)gew[2];
        for (int v = 0; v < 8; ++v) o2[v] = he[v] * dis[v] * dis[v] + (double)geb[0];
        for (int e = 0; e < 8; ++e) {
            int s = ei[e], d = ei[8 + e];
            o2[d] += he[s] * dis[s] * dis[d];
        }
        for (int j = 0; j < 8; ++j) {
            double a = (double)eb[j];
            for (int v = 0; v < 8; ++v) a += o2[v] * (double)ew[v * 8 + j];
            feats[9 + j] = a;
        }
        feats[17] = (double)p_norm[0];
        feats[18] = (double)theta[0];
    }
    __syncthreads();
    // gate matrices: layer l = 3*i + j uses angle qw[i, q, j]; store by bit
    for (int g = tid; g < 6 * NQ; g += blockDim.x) {
        int l = g / NQ, q = g % NQ;
        int i = l / 3, j = l % 3;
        double t = (double)qw[i * (NQ * 3) + q * 3 + j];
        double c = cos(0.5 * t), s = sin(0.5 * t);
        int k = 18 - q;
        double2* Ug = &G[(l * NQ + k) * 4];
        Ug[0] = make_double2(c * c, -s * c);
        Ug[1] = make_double2(-s * s, -c * s);
        Ug[2] = make_double2(s * s, -c * s);
        Ug[3] = make_double2(c * c, s * c);
    }
    // phase tables: phi(b) = sum_k feats[18-k]*bit_k(b) - S/2
    double S = 0.0;
    for (int q = 0; q < NQ; ++q) S += feats[q];
    for (int m = tid; m < 1024; m += blockDim.x) {
        double a = -0.5 * S;
        for (int k = 0; k < 10; ++k)
            if ((m >> k) & 1) a += feats[18 - k];
        T0[m] = a;
    }
    for (int m = tid; m < 512; m += blockDim.x) {
        double a = 0.0;
        for (int k = 0; k < 9; ++k)
            if ((m >> k) & 1) a += feats[8 - k];   // bit 10+k -> feats[18-(10+k)]
        T1[m] = a;
    }
}

// Post-(H+RZ) feature-map state, PRE-ring: amp(b) = 2^{-9.5} e^{i phi(b)}
__global__ __launch_bounds__(256)
void k_init(const double* __restrict__ T0, const double* __restrict__ T1,
            double2* __restrict__ out)
{
    unsigned i = blockIdx.x * 256u + threadIdx.x;
    double phi = T0[i & 1023u] + T1[i >> 10];
    double sp, cp;
    sincos(phi, &sp, &cp);
    const double amp = 1.0 / sqrt((double)SZ);
    out[i] = make_double2(amp * cp, amp * sp);
}

// Ring permutation inverse (bit space):
//   b = (c ^ (c>>1)) & 0x1FFFF ; b17 = c0^c17^c18 ; b18 = c0^c18
__device__ __forceinline__ unsigned pinv(unsigned c)
{
    unsigned y = (c ^ (c >> 1)) & 0x1FFFFu;
    unsigned c0 = c & 1u, c17 = (c >> 17) & 1u, c18 = (c >> 18) & 1u;
    return y | ((c0 ^ c17 ^ c18) << 17) | ((c0 ^ c18) << 18);
}

// Layer kernel A: gather previous ring (pinv) + apply 1q gates on bits 0..10.
// 256 blocks, block = index bits 11..18, 2048 amps in LDS (32 KiB).
__global__ __launch_bounds__(256)
void k_layerA(const double2* __restrict__ in, double2* __restrict__ out,
              const double2* __restrict__ G, int layer)
{
    __shared__ double2 sh[2048];
    unsigned base = blockIdx.x << 11;
    for (unsigned l = threadIdx.x; l < 2048u; l += 256u)
        sh[l] = in[pinv(base | l)];
    __syncthreads();
    const double2* Gl = G + layer * NQ * 4;
    for (int bit = 0; bit <= 10; ++bit) {
        double2 u00 = Gl[bit * 4 + 0], u01 = Gl[bit * 4 + 1];
        double2 u10 = Gl[bit * 4 + 2], u11 = Gl[bit * 4 + 3];
        unsigned m = 1u << bit;
        for (unsigned p = threadIdx.x; p < 1024u; p += 256u) {
            unsigned l0 = ((p >> bit) << (bit + 1)) | (p & (m - 1u));
            unsigned l1 = l0 | m;
            double2 a = sh[l0], b = sh[l1];
            double2 na, nb;
            na.x = u00.x * a.x - u00.y * a.y + u01.x * b.x - u01.y * b.y;
            na.y = u00.x * a.y + u00.y * a.x + u01.x * b.y + u01.y * b.x;
            nb.x = u10.x * a.x - u10.y * a.y + u11.x * b.x - u11.y * b.y;
            nb.y = u10.x * a.y + u10.y * a.x + u11.x * b.y + u11.y * b.x;
            sh[l0] = na;
            sh[l1] = nb;
        }
        __syncthreads();
    }
    for (unsigned l = threadIdx.x; l < 2048u; l += 256u)
        out[base | l] = sh[l];
}

// Layer kernel B: 1q gates on bits 11..18, in place.
// 256 blocks, block = index bits 3..10; local l = (bits 11..18)<<3 | bits 0..2.
__global__ __launch_bounds__(256)
void k_layerB(double2* __restrict__ buf, const double2* __restrict__ G, int layer)
{
    __shared__ double2 sh[2048];
    unsigned blk = blockIdx.x;
    for (unsigned l = threadIdx.x; l < 2048u; l += 256u) {
        unsigned idx = ((l >> 3) << 11) | (blk << 3) | (l & 7u);
        sh[l] = buf[idx];
    }
    __syncthreads();
    const double2* Gl = G + layer * NQ * 4;
    for (int bit = 11; bit <= 18; ++bit) {
        double2 u00 = Gl[bit * 4 + 0], u01 = Gl[bit * 4 + 1];
        double2 u10 = Gl[bit * 4 + 2], u11 = Gl[bit * 4 + 3];
        int lb = bit - 8;                     // amp bit 11..18 -> local bit 3..10
        unsigned m = 1u << lb;
        for (unsigned p = threadIdx.x; p < 1024u; p += 256u) {
            unsigned l0 = ((p >> lb) << (lb + 1)) | (p & (m - 1u));
            unsigned l1 = l0 | m;
            double2 a = sh[l0], b = sh[l1];
            double2 na, nb;
            na.x = u00.x * a.x - u00.y * a.y + u01.x * b.x - u01.y * b.y;
            na.y = u00.x * a.y + u00.y * a.x + u01.x * b.y + u01.y * b.x;
            nb.x = u10.x * a.x - u10.y * a.y + u11.x * b.x - u11.y * b.y;
            nb.y = u10.x * a.y + u10.y * a.x + u11.x * b.y + u11.y * b.x;
            sh[l0] = na;
            sh[l1] = nb;
        }
        __syncthreads();
    }
    for (unsigned l = threadIdx.x; l < 2048u; l += 256u) {
        unsigned idx = ((l >> 3) << 11) | (blk << 3) | (l & 7u);
        buf[idx] = sh[l];
    }
}

// Reduction with the final ring folded in as a sign twist:
//   <Z_0> = sum_b (-1)^{parity(b & 0x3FFFF)} |psi(b)|^2   (deterministic, fp64)
__global__ __launch_bounds__(256)
void k_reduce1(const double2* __restrict__ buf, double* __restrict__ partial)
{
    __shared__ double sm[256];
    double acc = 0.0;
    for (int k = 0; k < 8; ++k) {
        unsigned i = blockIdx.x * 2048u + (unsigned)k * 256u + threadIdx.x;
        double2 v = buf[i];
        double w = v.x * v.x + v.y * v.y;
        acc += (__popc(i & 0x3FFFFu) & 1) ? -w : w;
    }
    sm[threadIdx.x] = acc;
    __syncthreads();
    for (int st = 128; st > 0; st >>= 1) {
        if ((int)threadIdx.x < st) sm[threadIdx.x] += sm[threadIdx.x + st];
        __syncthreads();
    }
    if (threadIdx.x == 0) partial[blockIdx.x] = sm[0];
}

__global__ __launch_bounds__(256)
void k_reduce2(const double* __restrict__ partial, float* __restrict__ out)
{
    __shared__ double sm[256];
    sm[threadIdx.x] = partial[threadIdx.x];
    __syncthreads();
    for (int st = 128; st > 0; st >>= 1) {
        if ((int)threadIdx.x < st) sm[threadIdx.x] += sm[threadIdx.x + st];
        __syncthreads();
    }
    if (threadIdx.x == 0) out[0] = (float)sm[0];
}

extern "C" void kernel_launch(void* const* d_in, const int* in_sizes, int n_in,
                              void* d_out, int out_size, void* d_ws, size_t ws_size,
                              hipStream_t stream)
{
    const int*   ei      = (const int*)d_in[0];
    const float* state   = (const float*)d_in[1];
    const float* mass    = (const float*)d_in[2];
    const float* spin    = (const float*)d_in[3];
    const float* charge  = (const float*)d_in[4];
    const float* p_norm  = (const float*)d_in[5];
    const float* theta   = (const float*)d_in[6];
    // d_in[7] = scattering (unused by reference)
    const float* gnw     = (const float*)d_in[8];
    const float* gnb     = (const float*)d_in[9];
    const float* gew     = (const float*)d_in[10];
    const float* geb     = (const float*)d_in[11];
    const float* nw      = (const float*)d_in[12];
    const float* nb      = (const float*)d_in[13];
    const float* ew      = (const float*)d_in[14];
    const float* eb      = (const float*)d_in[15];
    const float* qw      = (const float*)d_in[16];

    char* ws = (char*)d_ws;
    double2* G       = (double2*)(ws);                 // 6*19*4*16 = 7296 B
    double*  T0      = (double*)(ws + 8192);           // 8 KiB
    double*  T1      = (double*)(ws + 16384);          // 4 KiB
    double*  partial = (double*)(ws + 20480);          // 2 KiB
    double2* buf0    = (double2*)(ws + 32768);         // 8 MiB
    double2* buf1    = buf0 + SZ;                      // 8 MiB

    k_prep<<<1, 128, 0, stream>>>(ei, state, mass, spin, charge, p_norm, theta,
                                  gnw, gnb, gew, geb, nw, nb, ew, eb, qw,
                                  G, T0, T1);
    k_init<<<SZ / 256, 256, 0, stream>>>(T0, T1, buf0);

    double2* bufs[2] = {buf0, buf1};
    for (int l = 0; l < 6; ++l) {
        double2* in  = bufs[l & 1];
        double2* out = bufs[(l & 1) ^ 1];
        k_layerA<<<256, 256, 0, stream>>>(in, out, G, l);
        k_layerB<<<256, 256, 0, stream>>>(out, G, l);
    }
    // after l=5: final (pre-ring) state is in buf0
    k_reduce1<<<256, 256, 0, stream>>>(buf0, partial);
    k_reduce2<<<1, 256, 0, stream>>>(partial, (float*)d_out);
}

// Round 2
// 123.257 us; speedup vs baseline: 1.5773x; 1.5773x over previous
//
#include <hip/hip_runtime.h>

#define NQ 19
#define SZ (1u << NQ)

// ---------------------------------------------------------------------------
// Prep (1 block): GCN front-end in fp64 -> feats[19]; fused gate matrices
// G[6][19(bit)][4] in fp32; phase-factor tables E0[1024] (bits 0..9, includes
// global -S/2 phase and 2^-9.5 amplitude... amplitude folded into E1) and
// E1[512] (bits 10..18).
// Qubit q <-> flat-index bit k = 18 - q (C-order flatten of (2,)*19).
// Fused ansatz 1q gate U = RZ(t)*RX(t), c=cos(t/2), s=sin(t/2):
//   u00=(c^2,-sc) u01=(-s^2,-cs) u10=(s^2,-cs) u11=(c^2,sc)
// ---------------------------------------------------------------------------
__global__ __launch_bounds__(128)
void k_prep(const int* __restrict__ ei, const float* __restrict__ state,
            const float* __restrict__ mass, const float* __restrict__ spin,
            const float* __restrict__ charge, const float* __restrict__ p_norm,
            const float* __restrict__ theta,
            const float* __restrict__ gnw, const float* __restrict__ gnb,
            const float* __restrict__ gew, const float* __restrict__ geb,
            const float* __restrict__ nw, const float* __restrict__ nb,
            const float* __restrict__ ew, const float* __restrict__ eb,
            const float* __restrict__ qw,
            float2* __restrict__ G, float2* __restrict__ E0,
            float2* __restrict__ E1)
{
    __shared__ double feats[NQ];
    int tid = threadIdx.x;
    if (tid == 0) {
        double deg[8], dis[8], h[8], o1[8], he[8], o2[8];
        for (int v = 0; v < 8; ++v) deg[v] = 1.0;                 // self loops
        for (int e = 0; e < 8; ++e) deg[ei[8 + e]] += 1.0;
        for (int v = 0; v < 8; ++v) dis[v] = 1.0 / sqrt(deg[v]);
        for (int v = 0; v < 8; ++v) {
            double s = 0.0;
            for (int k = 0; k < 4; ++k) s += (double)state[v * 4 + k] * (double)gnw[k];
            h[v] = s;
        }
        for (int v = 0; v < 8; ++v) o1[v] = h[v] * dis[v] * dis[v] + (double)gnb[0];
        for (int e = 0; e < 8; ++e) {
            int s = ei[e], d = ei[8 + e];
            o1[d] += h[s] * dis[s] * dis[d];
        }
        for (int j = 0; j < 9; ++j) {
            double a = (double)nb[j];
            for (int v = 0; v < 8; ++v) a += o1[v] * (double)nw[v * 9 + j];
            feats[j] = a;
        }
        for (int e = 0; e < 8; ++e)
            he[e] = (double)mass[e] * (double)gew[0] + (double)spin[e] * (double)gew[1]
                  + (double)charge[e] * (double)gew[2];
        for (int v = 0; v < 8; ++v) o2[v] = he[v] * dis[v] * dis[v] + (double)geb[0];
        for (int e = 0; e < 8; ++e) {
            int s = ei[e], d = ei[8 + e];
            o2[d] += he[s] * dis[s] * dis[d];
        }
        for (int j = 0; j < 8; ++j) {
            double a = (double)eb[j];
            for (int v = 0; v < 8; ++v) a += o2[v] * (double)ew[v * 8 + j];
            feats[9 + j] = a;
        }
        feats[17] = (double)p_norm[0];
        feats[18] = (double)theta[0];
    }
    __syncthreads();
    // gate matrices: layer l = 3*i + j uses angle qw[i, q, j]; store by bit
    for (int g = tid; g < 6 * NQ; g += blockDim.x) {
        int l = g / NQ, q = g % NQ;
        int i = l / 3, j = l % 3;
        double t = (double)qw[i * (NQ * 3) + q * 3 + j];
        double c = cos(0.5 * t), s = sin(0.5 * t);
        int k = 18 - q;
        float2* Ug = &G[(l * NQ + k) * 4];
        Ug[0] = make_float2((float)(c * c), (float)(-s * c));
        Ug[1] = make_float2((float)(-s * s), (float)(-c * s));
        Ug[2] = make_float2((float)(s * s), (float)(-c * s));
        Ug[3] = make_float2((float)(c * c), (float)(s * c));
    }
    // phase tables: phi(b) = sum_k feats[18-k]*bit_k(b) - S/2
    double S = 0.0;
    for (int q = 0; q < NQ; ++q) S += feats[q];
    for (int m = tid; m < 1024; m += blockDim.x) {
        double a = -0.5 * S;
        for (int k = 0; k < 10; ++k)
            if ((m >> k) & 1) a += feats[18 - k];
        double sp, cp;
        sincos(a, &sp, &cp);
        E0[m] = make_float2((float)cp, (float)sp);
    }
    const double amp = 1.0 / sqrt((double)SZ);
    for (int m = tid; m < 512; m += blockDim.x) {
        double a = 0.0;
        for (int k = 0; k < 9; ++k)
            if ((m >> k) & 1) a += feats[8 - k];   // bit 10+k -> feats[18-(10+k)]
        double sp, cp;
        sincos(a, &sp, &cp);
        E1[m] = make_float2((float)(amp * cp), (float)(amp * sp));
    }
}

// Ring permutation inverse (bit space):
//   b = (c ^ (c>>1)) & 0x1FFFF ; b17 = c0^c17^c18 ; b18 = c0^c18
__device__ __forceinline__ unsigned pinv(unsigned c)
{
    unsigned y = (c ^ (c >> 1)) & 0x1FFFFu;
    unsigned c0 = c & 1u, c17 = (c >> 17) & 1u, c18 = (c >> 18) & 1u;
    return y | ((c0 ^ c17 ^ c18) << 17) | ((c0 ^ c18) << 18);
}

__device__ __forceinline__ void butterfly(float2& a, float2& b,
                                          float2 u00, float2 u01,
                                          float2 u10, float2 u11)
{
    float2 na, nb;
    na.x = u00.x * a.x - u00.y * a.y + u01.x * b.x - u01.y * b.y;
    na.y = u00.x * a.y + u00.y * a.x + u01.x * b.y + u01.y * b.x;
    nb.x = u10.x * a.x - u10.y * a.y + u11.x * b.x - u11.y * b.y;
    nb.y = u10.x * a.y + u10.y * a.x + u11.x * b.y + u11.y * b.x;
    a = na;
    b = nb;
}

// Layer kernel A: gather previous ring (pinv) + apply 1q gates on bits 0..10.
// 256 blocks x 512 threads; block = index bits 11..18; 2048 amps in LDS.
// first!=0: synthesize the post-(H+RZ) feature-map state from E0/E1 instead
// of reading a global buffer (fuses the init pass).
__global__ __launch_bounds__(512)
void k_layerA(const float2* __restrict__ in, float2* __restrict__ out,
              const float2* __restrict__ G, int layer,
              const float2* __restrict__ E0, const float2* __restrict__ E1,
              int first)
{
    __shared__ float2 sh[2048];
    unsigned base = blockIdx.x << 11;
    if (first) {
        for (unsigned l = threadIdx.x; l < 2048u; l += 512u) {
            unsigned b = pinv(base | l);
            float2 e0 = E0[b & 1023u], e1 = E1[b >> 10];
            sh[l] = make_float2(e0.x * e1.x - e0.y * e1.y,
                                e0.x * e1.y + e0.y * e1.x);
        }
    } else {
        for (unsigned l = threadIdx.x; l < 2048u; l += 512u)
            sh[l] = in[pinv(base | l)];
    }
    __syncthreads();
    const float2* Gl = G + layer * NQ * 4;
    for (int bit = 0; bit <= 10; ++bit) {
        float2 u00 = Gl[bit * 4 + 0], u01 = Gl[bit * 4 + 1];
        float2 u10 = Gl[bit * 4 + 2], u11 = Gl[bit * 4 + 3];
        unsigned m = 1u << bit;
        for (unsigned p = threadIdx.x; p < 1024u; p += 512u) {
            unsigned l0 = ((p >> bit) << (bit + 1)) | (p & (m - 1u));
            unsigned l1 = l0 | m;
            float2 a = sh[l0], b = sh[l1];
            butterfly(a, b, u00, u01, u10, u11);
            sh[l0] = a;
            sh[l1] = b;
        }
        __syncthreads();
    }
    for (unsigned l = threadIdx.x; l < 2048u; l += 512u)
        out[base | l] = sh[l];
}

// Layer kernel B: 1q gates on bits 11..18, in place.
// 256 blocks x 512 threads; block = index bits 3..10;
// local l = (bits 11..18)<<3 | bits 0..2.
// do_reduce!=0 (last layer): instead of writing the state back, fold the
// final CNOT ring + <Z_0> into a sign-twisted |amp|^2 partial sum (fp64):
//   <Z_0> = sum_b (-1)^{parity(b & 0x3FFFF)} |psi_preRing(b)|^2
__global__ __launch_bounds__(512)
void k_layerB(float2* __restrict__ buf, const float2* __restrict__ G, int layer,
              int do_reduce, double* __restrict__ partial)
{
    __shared__ float2 sh[2048];
    unsigned blk = blockIdx.x;
    for (unsigned l = threadIdx.x; l < 2048u; l += 512u) {
        unsigned idx = ((l >> 3) << 11) | (blk << 3) | (l & 7u);
        sh[l] = buf[idx];
    }
    __syncthreads();
    const float2* Gl = G + layer * NQ * 4;
    for (int bit = 11; bit <= 18; ++bit) {
        float2 u00 = Gl[bit * 4 + 0], u01 = Gl[bit * 4 + 1];
        float2 u10 = Gl[bit * 4 + 2], u11 = Gl[bit * 4 + 3];
        int lb = bit - 8;                     // amp bit 11..18 -> local bit 3..10
        unsigned m = 1u << lb;
        for (unsigned p = threadIdx.x; p < 1024u; p += 512u) {
            unsigned l0 = ((p >> lb) << (lb + 1)) | (p & (m - 1u));
            unsigned l1 = l0 | m;
            float2 a = sh[l0], b = sh[l1];
            butterfly(a, b, u00, u01, u10, u11);
            sh[l0] = a;
            sh[l1] = b;
        }
        __syncthreads();
    }
    if (do_reduce) {
        __shared__ double sm[512];
        double acc = 0.0;
        for (unsigned l = threadIdx.x; l < 2048u; l += 512u) {
            unsigned idx = ((l >> 3) << 11) | (blk << 3) | (l & 7u);
            float2 v = sh[l];
            double w = (double)v.x * v.x + (double)v.y * v.y;
            acc += (__popc(idx & 0x3FFFFu) & 1) ? -w : w;
        }
        sm[threadIdx.x] = acc;
        __syncthreads();
        for (int st = 256; st > 0; st >>= 1) {
            if ((int)threadIdx.x < st) sm[threadIdx.x] += sm[threadIdx.x + st];
            __syncthreads();
        }
        if (threadIdx.x == 0) partial[blk] = sm[0];
    } else {
        for (unsigned l = threadIdx.x; l < 2048u; l += 512u) {
            unsigned idx = ((l >> 3) << 11) | (blk << 3) | (l & 7u);
            buf[idx] = sh[l];
        }
    }
}

__global__ __launch_bounds__(256)
void k_final(const double* __restrict__ partial, float* __restrict__ out)
{
    __shared__ double sm[256];
    sm[threadIdx.x] = partial[threadIdx.x];
    __syncthreads();
    for (int st = 128; st > 0; st >>= 1) {
        if ((int)threadIdx.x < st) sm[threadIdx.x] += sm[threadIdx.x + st];
        __syncthreads();
    }
    if (threadIdx.x == 0) out[0] = (float)sm[0];
}

extern "C" void kernel_launch(void* const* d_in, const int* in_sizes, int n_in,
                              void* d_out, int out_size, void* d_ws, size_t ws_size,
                              hipStream_t stream)
{
    const int*   ei      = (const int*)d_in[0];
    const float* state   = (const float*)d_in[1];
    const float* mass    = (const float*)d_in[2];
    const float* spin    = (const float*)d_in[3];
    const float* charge  = (const float*)d_in[4];
    const float* p_norm  = (const float*)d_in[5];
    const float* theta   = (const float*)d_in[6];
    // d_in[7] = scattering (unused by reference)
    const float* gnw     = (const float*)d_in[8];
    const float* gnb     = (const float*)d_in[9];
    const float* gew     = (const float*)d_in[10];
    const float* geb     = (const float*)d_in[11];
    const float* nw      = (const float*)d_in[12];
    const float* nb      = (const float*)d_in[13];
    const float* ew      = (const float*)d_in[14];
    const float* eb      = (const float*)d_in[15];
    const float* qw      = (const float*)d_in[16];

    char* ws = (char*)d_ws;
    float2* G       = (float2*)(ws);                  // 6*19*4*8 = 3648 B
    float2* E0      = (float2*)(ws + 4096);           // 8 KiB
    float2* E1      = (float2*)(ws + 12288);          // 4 KiB
    double* partial = (double*)(ws + 16384);          // 2 KiB
    float2* buf0    = (float2*)(ws + 32768);          // 4 MiB
    float2* buf1    = buf0 + SZ;                      // 4 MiB

    k_prep<<<1, 128, 0, stream>>>(ei, state, mass, spin, charge, p_norm, theta,
                                  gnw, gnb, gew, geb, nw, nb, ew, eb, qw,
                                  G, E0, E1);

    float2* bufs[2] = {buf0, buf1};
    for (int l = 0; l < 6; ++l) {
        float2* in  = bufs[l & 1];
        float2* out = bufs[(l & 1) ^ 1];
        k_layerA<<<256, 512, 0, stream>>>(in, out, G, l, E0, E1, l == 0);
        k_layerB<<<256, 512, 0, stream>>>(out, G, l, l == 5, partial);
    }
    k_final<<<1, 256, 0, stream>>>(partial, (float*)d_out);
}

// Round 3
// 98.986 us; speedup vs baseline: 1.9640x; 1.2452x over previous
//
#include <hip/hip_runtime.h>

#define NQ 19
#define SZ (1u << NQ)

// ---------------------------------------------------------------------------
// Prep (1 block): GCN front-end in fp64 -> feats[19]; fused gate matrices
// G[6][19(bit)][4] fp32; phase-factor tables E0[1024] (bits 0..9, includes
// global -S/2 phase) and E1[512] (bits 10..18, includes 2^-9.5 amplitude).
// Qubit q <-> flat-index bit k = 18 - q. Fused 1q gate U = RZ(t)*RX(t).
// ---------------------------------------------------------------------------
__global__ __launch_bounds__(128)
void k_prep(const int* __restrict__ ei, const float* __restrict__ state,
            const float* __restrict__ mass, const float* __restrict__ spin,
            const float* __restrict__ charge, const float* __restrict__ p_norm,
            const float* __restrict__ theta,
            const float* __restrict__ gnw, const float* __restrict__ gnb,
            const float* __restrict__ gew, const float* __restrict__ geb,
            const float* __restrict__ nw, const float* __restrict__ nb,
            const float* __restrict__ ew, const float* __restrict__ eb,
            const float* __restrict__ qw,
            float2* __restrict__ G, float2* __restrict__ E0,
            float2* __restrict__ E1)
{
    __shared__ double feats[NQ];
    int tid = threadIdx.x;
    if (tid == 0) {
        double deg[8], dis[8], h[8], o1[8], he[8], o2[8];
        for (int v = 0; v < 8; ++v) deg[v] = 1.0;                 // self loops
        for (int e = 0; e < 8; ++e) deg[ei[8 + e]] += 1.0;
        for (int v = 0; v < 8; ++v) dis[v] = 1.0 / sqrt(deg[v]);
        for (int v = 0; v < 8; ++v) {
            double s = 0.0;
            for (int k = 0; k < 4; ++k) s += (double)state[v * 4 + k] * (double)gnw[k];
            h[v] = s;
        }
        for (int v = 0; v < 8; ++v) o1[v] = h[v] * dis[v] * dis[v] + (double)gnb[0];
        for (int e = 0; e < 8; ++e) {
            int s = ei[e], d = ei[8 + e];
            o1[d] += h[s] * dis[s] * dis[d];
        }
        for (int j = 0; j < 9; ++j) {
            double a = (double)nb[j];
            for (int v = 0; v < 8; ++v) a += o1[v] * (double)nw[v * 9 + j];
            feats[j] = a;
        }
        for (int e = 0; e < 8; ++e)
            he[e] = (double)mass[e] * (double)gew[0] + (double)spin[e] * (double)gew[1]
                  + (double)charge[e] * (double)gew[2];
        for (int v = 0; v < 8; ++v) o2[v] = he[v] * dis[v] * dis[v] + (double)geb[0];
        for (int e = 0; e < 8; ++e) {
            int s = ei[e], d = ei[8 + e];
            o2[d] += he[s] * dis[s] * dis[d];
        }
        for (int j = 0; j < 8; ++j) {
            double a = (double)eb[j];
            for (int v = 0; v < 8; ++v) a += o2[v] * (double)ew[v * 8 + j];
            feats[9 + j] = a;
        }
        feats[17] = (double)p_norm[0];
        feats[18] = (double)theta[0];
    }
    __syncthreads();
    for (int g = tid; g < 6 * NQ; g += blockDim.x) {
        int l = g / NQ, q = g % NQ;
        int i = l / 3, j = l % 3;
        double t = (double)qw[i * (NQ * 3) + q * 3 + j];
        double c = cos(0.5 * t), s = sin(0.5 * t);
        int k = 18 - q;
        float2* Ug = &G[(l * NQ + k) * 4];
        Ug[0] = make_float2((float)(c * c), (float)(-s * c));
        Ug[1] = make_float2((float)(-s * s), (float)(-c * s));
        Ug[2] = make_float2((float)(s * s), (float)(-c * s));
        Ug[3] = make_float2((float)(c * c), (float)(s * c));
    }
    double S = 0.0;
    for (int q = 0; q < NQ; ++q) S += feats[q];
    for (int m = tid; m < 1024; m += blockDim.x) {
        double a = -0.5 * S;
        for (int k = 0; k < 10; ++k)
            if ((m >> k) & 1) a += feats[18 - k];
        double sp, cp;
        sincos(a, &sp, &cp);
        E0[m] = make_float2((float)cp, (float)sp);
    }
    const double amp = 1.0 / sqrt((double)SZ);
    for (int m = tid; m < 512; m += blockDim.x) {
        double a = 0.0;
        for (int k = 0; k < 9; ++k)
            if ((m >> k) & 1) a += feats[8 - k];
        double sp, cp;
        sincos(a, &sp, &cp);
        E1[m] = make_float2((float)(amp * cp), (float)(amp * sp));
    }
}

// Ring permutation inverse (bit space):
//   b = (c ^ (c>>1)) & 0x1FFFF ; b17 = c0^c17^c18 ; b18 = c0^c18
__device__ __forceinline__ unsigned pinv(unsigned c)
{
    unsigned y = (c ^ (c >> 1)) & 0x1FFFFu;
    unsigned c0 = c & 1u, c17 = (c >> 17) & 1u, c18 = (c >> 18) & 1u;
    return y | ((c0 ^ c17 ^ c18) << 17) | ((c0 ^ c18) << 18);
}

// Padded LDS index: +2 float2 per 8 -> all exchange patterns <= 2-way.
__device__ __forceinline__ unsigned padl(unsigned l) { return l + 2u * (l >> 3); }

__device__ __forceinline__ void bfly(float2& a, float2& b,
                                     float2 u00, float2 u01,
                                     float2 u10, float2 u11)
{
    float2 na, nb;
    na.x = u00.x * a.x - u00.y * a.y + u01.x * b.x - u01.y * b.y;
    na.y = u00.x * a.y + u00.y * a.x + u01.x * b.y + u01.y * b.x;
    nb.x = u10.x * a.x - u10.y * a.y + u11.x * b.x - u11.y * b.y;
    nb.y = u10.x * a.y + u10.y * a.x + u11.x * b.y + u11.y * b.x;
    a = na;
    b = nb;
}

// Apply n gates (amp bits ampbit0..), register j-bits jbit0.. of r[8].
__device__ __forceinline__ void apply_gates(float2 r[8], const float2* __restrict__ Gl,
                                            int ampbit0, int jbit0, int n)
{
    #pragma unroll
    for (int k = 0; k < n; ++k) {
        const float2 u00 = Gl[(ampbit0 + k) * 4 + 0];
        const float2 u01 = Gl[(ampbit0 + k) * 4 + 1];
        const float2 u10 = Gl[(ampbit0 + k) * 4 + 2];
        const float2 u11 = Gl[(ampbit0 + k) * 4 + 3];
        const int m = 1 << (jbit0 + k);
        #pragma unroll
        for (int j = 0; j < 8; ++j)
            if (!(j & m)) bfly(r[j], r[j | m], u00, u01, u10, u11);
    }
}

// ---------------------------------------------------------------------------
// Pass A: gather previous ring (pinv) + gates on amp bits 0..10.
// 256 blocks x 256 threads; block = amp bits 11..18; 8 amps/thread.
// Phases: regs={0,1,2} (from load) -> {3,4,5} -> {6,7,8} -> {0,9,10}.
// 3 barriers total (double-buffered LDS exchanges).
// ---------------------------------------------------------------------------
__global__ __launch_bounds__(256)
void k_layerA(const float2* __restrict__ in, float2* __restrict__ out,
              const float2* __restrict__ G, int layer,
              const float2* __restrict__ E0, const float2* __restrict__ E1,
              int first)
{
    __shared__ __align__(16) float2 lds0[2560];
    __shared__ __align__(16) float2 lds1[2560];
    const unsigned t = threadIdx.x;
    const unsigned base = blockIdx.x << 11;
    const float2* Gl = G + layer * NQ * 4;
    float2 r[8];

    if (first) {
        #pragma unroll
        for (int j = 0; j < 8; ++j) {
            unsigned b = pinv(base | (t * 8u + (unsigned)j));
            float2 e0 = E0[b & 1023u], e1 = E1[b >> 10];
            r[j] = make_float2(e0.x * e1.x - e0.y * e1.y,
                               e0.x * e1.y + e0.y * e1.x);
        }
    } else {
        #pragma unroll
        for (int j = 0; j < 8; ++j)
            r[j] = in[pinv(base | (t * 8u + (unsigned)j))];
    }
    apply_gates(r, Gl, 0, 0, 3);

    // exchange -> regs amp bits {3,4,5}
    #pragma unroll
    for (int jh = 0; jh < 4; ++jh) {
        unsigned l = t * 8u + (unsigned)jh * 2u;
        *reinterpret_cast<float4*>(&lds0[padl(l)]) =
            make_float4(r[2 * jh].x, r[2 * jh].y, r[2 * jh + 1].x, r[2 * jh + 1].y);
    }
    __syncthreads();
    #pragma unroll
    for (int j = 0; j < 8; ++j)
        r[j] = lds0[padl((t & 7u) | ((unsigned)j << 3) | ((t >> 3) << 6))];
    apply_gates(r, Gl, 3, 0, 3);

    // exchange -> regs amp bits {6,7,8}
    #pragma unroll
    for (int j = 0; j < 8; ++j)
        lds1[padl((t & 7u) | ((unsigned)j << 3) | ((t >> 3) << 6))] = r[j];
    __syncthreads();
    #pragma unroll
    for (int j = 0; j < 8; ++j)
        r[j] = lds1[padl((t & 63u) | ((unsigned)j << 6) | ((t >> 6) << 9))];
    apply_gates(r, Gl, 6, 0, 3);

    // exchange -> regs amp bits {0,9,10}
    #pragma unroll
    for (int j = 0; j < 8; ++j)
        lds0[padl((t & 63u) | ((unsigned)j << 6) | ((t >> 6) << 9))] = r[j];
    __syncthreads();
    #pragma unroll
    for (int jh = 0; jh < 4; ++jh) {
        float4 v = *reinterpret_cast<const float4*>(
            &lds0[padl((t << 1) | ((unsigned)jh << 9))]);
        r[2 * jh]     = make_float2(v.x, v.y);
        r[2 * jh + 1] = make_float2(v.z, v.w);
    }
    apply_gates(r, Gl, 9, 1, 2);

    // writeback (coalesced float4)
    #pragma unroll
    for (int jh = 0; jh < 4; ++jh) {
        unsigned l = (t << 1) | ((unsigned)jh << 9);
        *reinterpret_cast<float4*>(&out[base | l]) =
            make_float4(r[2 * jh].x, r[2 * jh].y, r[2 * jh + 1].x, r[2 * jh + 1].y);
    }
}

// ---------------------------------------------------------------------------
// Pass B: gates on amp bits 11..18, in place. 256 blocks x 256 threads.
// Block local index l: bits {0..2} = amp bits 0..2, bits {3..10} = amp 11..18;
// block id = amp bits 3..10. Phases: regs={11,12,13} -> {14,15,16} -> {0,17,18}.
// do_reduce (last layer): fold final CNOT ring + <Z_0> into sign-twisted
// fp64 partial sums instead of writing the state back.
// ---------------------------------------------------------------------------
__global__ __launch_bounds__(256)
void k_layerB(float2* __restrict__ buf, const float2* __restrict__ G, int layer,
              int do_reduce, double* __restrict__ partial)
{
    __shared__ __align__(16) float2 lds0[2560];
    __shared__ __align__(16) float2 lds1[2560];
    const unsigned t = threadIdx.x;
    const unsigned blk = blockIdx.x;
    const float2* Gl = G + layer * NQ * 4;
    float2 r[8];

    // load: regs = amp bits {11,12,13}
    #pragma unroll
    for (int j = 0; j < 8; ++j) {
        unsigned g = (blk << 3) | (t & 7u) | ((unsigned)j << 11) | ((t >> 3) << 14);
        r[j] = buf[g];
    }
    apply_gates(r, Gl, 11, 0, 3);

    // exchange -> regs amp bits {14,15,16}
    #pragma unroll
    for (int j = 0; j < 8; ++j)
        lds0[padl((t & 7u) | ((unsigned)j << 3) | ((t >> 3) << 6))] = r[j];
    __syncthreads();
    #pragma unroll
    for (int j = 0; j < 8; ++j)
        r[j] = lds0[padl((t & 63u) | ((unsigned)j << 6) | ((t >> 6) << 9))];
    apply_gates(r, Gl, 14, 0, 3);

    // exchange -> regs amp bits {0,17,18}
    #pragma unroll
    for (int j = 0; j < 8; ++j)
        lds1[padl((t & 63u) | ((unsigned)j << 6) | ((t >> 6) << 9))] = r[j];
    __syncthreads();
    #pragma unroll
    for (int jh = 0; jh < 4; ++jh) {
        float4 v = *reinterpret_cast<const float4*>(
            &lds1[padl((t << 1) | ((unsigned)jh << 9))]);
        r[2 * jh]     = make_float2(v.x, v.y);
        r[2 * jh + 1] = make_float2(v.z, v.w);
    }
    apply_gates(r, Gl, 17, 1, 2);

    if (do_reduce) {
        __shared__ double sm[256];
        double acc = 0.0;
        #pragma unroll
        for (int jh = 0; jh < 4; ++jh) {
            unsigned l0 = (t << 1) | ((unsigned)jh << 9);
            unsigned g0 = (blk << 3) | (l0 & 7u) | ((l0 >> 3) << 11);
            float2 a = r[2 * jh], b = r[2 * jh + 1];
            double w0 = (double)a.x * a.x + (double)a.y * a.y;
            double w1 = (double)b.x * b.x + (double)b.y * b.y;
            double d = w0 - w1;                 // g1 = g0|1 flips parity
            acc += (__popc(g0 & 0x3FFFFu) & 1) ? -d : d;
        }
        sm[t] = acc;
        __syncthreads();
        for (int st = 128; st > 0; st >>= 1) {
            if ((int)t < st) sm[t] += sm[t + st];
            __syncthreads();
        }
        if (t == 0) partial[blk] = sm[0];
    } else {
        #pragma unroll
        for (int jh = 0; jh < 4; ++jh) {
            unsigned l = (t << 1) | ((unsigned)jh << 9);
            unsigned g = (blk << 3) | (l & 7u) | ((l >> 3) << 11);
            *reinterpret_cast<float4*>(&buf[g]) =
                make_float4(r[2 * jh].x, r[2 * jh].y, r[2 * jh + 1].x, r[2 * jh + 1].y);
        }
    }
}

__global__ __launch_bounds__(256)
void k_final(const double* __restrict__ partial, float* __restrict__ out)
{
    __shared__ double sm[256];
    sm[threadIdx.x] = partial[threadIdx.x];
    __syncthreads();
    for (int st = 128; st > 0; st >>= 1) {
        if ((int)threadIdx.x < st) sm[threadIdx.x] += sm[threadIdx.x + st];
        __syncthreads();
    }
    if (threadIdx.x == 0) out[0] = (float)sm[0];
}

extern "C" void kernel_launch(void* const* d_in, const int* in_sizes, int n_in,
                              void* d_out, int out_size, void* d_ws, size_t ws_size,
                              hipStream_t stream)
{
    const int*   ei      = (const int*)d_in[0];
    const float* state   = (const float*)d_in[1];
    const float* mass    = (const float*)d_in[2];
    const float* spin    = (const float*)d_in[3];
    const float* charge  = (const float*)d_in[4];
    const float* p_norm  = (const float*)d_in[5];
    const float* theta   = (const float*)d_in[6];
    // d_in[7] = scattering (unused by reference)
    const float* gnw     = (const float*)d_in[8];
    const float* gnb     = (const float*)d_in[9];
    const float* gew     = (const float*)d_in[10];
    const float* geb     = (const float*)d_in[11];
    const float* nw      = (const float*)d_in[12];
    const float* nb      = (const float*)d_in[13];
    const float* ew      = (const float*)d_in[14];
    const float* eb      = (const float*)d_in[15];
    const float* qw      = (const float*)d_in[16];

    char* ws = (char*)d_ws;
    float2* G       = (float2*)(ws);                  // 6*19*4*8 = 3648 B
    float2* E0      = (float2*)(ws + 4096);           // 8 KiB
    float2* E1      = (float2*)(ws + 12288);          // 4 KiB
    double* partial = (double*)(ws + 16384);          // 2 KiB
    float2* buf0    = (float2*)(ws + 32768);          // 4 MiB
    float2* buf1    = buf0 + SZ;                      // 4 MiB

    k_prep<<<1, 128, 0, stream>>>(ei, state, mass, spin, charge, p_norm, theta,
                                  gnw, gnb, gew, geb, nw, nb, ew, eb, qw,
                                  G, E0, E1);

    float2* bufs[2] = {buf0, buf1};
    for (int l = 0; l < 6; ++l) {
        float2* in  = bufs[l & 1];
        float2* out = bufs[(l & 1) ^ 1];
        k_layerA<<<256, 256, 0, stream>>>(in, out, G, l, E0, E1, l == 0);
        k_layerB<<<256, 256, 0, stream>>>(out, G, l, l == 5, partial);
    }
    k_final<<<1, 256, 0, stream>>>(partial, (float*)d_out);
}